// Round 1
// 745.659 us; speedup vs baseline: 1.0782x; 1.0782x over previous
//
#include <hip/hip_runtime.h>
#include <hip/hip_bf16.h>
#include <stdint.h>

// Problem dims (fixed by reference): B,C,F,W,H,K,S = 64,256,512,64,64,3,1
#define C_DIM 256
#define F_DIM 512
#define B_DIM 64
#define N_DIM 4096          // W*H
#define BN 128              // n per block (one b, one n-tile per block)
#define BF 128              // f per f-tile (4 f-tiles looped inside block)
#define BK 64               // k step
#define NSTEP 16            // 4 ft * 4 kt

typedef __bf16  bf16x8 __attribute__((ext_vector_type(8)));
typedef float   f32x4  __attribute__((ext_vector_type(4)));

// ---------------- prep: W2[f][c] = sum_{3x3} tanh(w + 0.5*log(eps/(1-eps))) ----------------
// tanh(w + 0.5*ln r) = (e^{2w} r - 1)/(e^{2w} r + 1) = 1 - 2/(e^{2w} r + 1); inf-safe form.
__global__ void prep_w2(const float* __restrict__ w, const float* __restrict__ eps,
                        __hip_bfloat16* __restrict__ w2) {
    int id = blockIdx.x * blockDim.x + threadIdx.x;          // [0, F*C)
    if (id >= F_DIM * C_DIM) return;
    const float* wp = w  + id * 9;
    const float* ep = eps + id * 9;
    float s = 0.f;
#pragma unroll
    for (int i = 0; i < 9; ++i) {
        float wi = wp[i], e = ep[i];
        float r = e / (1.0f - e);
        float t = __expf(2.0f * wi) * r;
        s += 1.0f - 2.0f / (t + 1.0f);
    }
    w2[id] = __float2bfloat16(s);
}

// ---------------- helpers ----------------
__device__ inline void load_lds16(const void* g, void* l) {
    __builtin_amdgcn_global_load_lds(
        (const __attribute__((address_space(1))) uint32_t*)g,
        (__attribute__((address_space(3))) uint32_t*)l, 16, 0, 0);
}

__device__ inline uint32_t pack_bf16x2(float a, float b) {
    union { __hip_bfloat162 h; uint32_t u; } c;
    c.h.x = __float2bfloat16(a);
    c.h.y = __float2bfloat16(b);
    return c.u;
}

// ---------------- GEMM: out[b][f][n] = sum_c W2[f][c] * X[b][c][n] ----------------
// One block per (b, n-tile). X tile staged to LDS ONCE (bf16, XOR-swizzled),
// then all 4 f-tiles computed from it. A (W2) tiles staged per k-step via
// global_load_lds with source-pre-swizzled addresses (linear LDS dest).
__global__ __launch_bounds__(512, 4)
void gemm_kernel(const float* __restrict__ X,
                 const __hip_bfloat16* __restrict__ W2,
                 float* __restrict__ Out) {
    // sX: [n][c] bf16, 512B rows, col-bytes XOR'd with ((n&31)<<4)  -> 64 KB
    __shared__ unsigned char sX[BN * 512];
    // sA: [f][k] bf16, 128B rows, 16B-group g holds src group (g ^ (m&7)) -> 16 KB
    __shared__ unsigned char sA[BF * BK * 2];

    const int tid  = threadIdx.x;
    const int lane = tid & 63;
    const int wave = tid >> 6;
    const int l15  = lane & 15;
    const int l4   = lane >> 4;

    const int bi = blockIdx.x >> 5;          // batch  [0,64)
    const int ni = blockIdx.x & 31;          // n-tile [0,32)

    const float* Xb = X   + (size_t)bi * C_DIM * N_DIM + ni * BN;
    float*       Ob = Out + (size_t)bi * F_DIM * N_DIM + ni * BN;

    // ---- stage Xt once: fp32 strided-row gather (coalesced along n), cvt, swizzled b128 writes ----
    {
        const int n  = tid & 127;            // lane-consecutive -> coalesced 256B loads
        const int ch = tid >> 7;             // 0..3 -> c range [ch*64, ch*64+64)
        unsigned char* base = sX + n * 512;
        const int sw = (n & 31) << 4;
        const float* xp = Xb + n;
#pragma unroll
        for (int g = 0; g < 8; ++g) {
            const int c0 = ch * 64 + g * 8;
            float v[8];
#pragma unroll
            for (int r = 0; r < 8; ++r)
                v[r] = __builtin_nontemporal_load(xp + (size_t)(c0 + r) * N_DIM);
            uint4 pk;
            pk.x = pack_bf16x2(v[0], v[1]);
            pk.y = pack_bf16x2(v[2], v[3]);
            pk.z = pack_bf16x2(v[4], v[5]);
            pk.w = pack_bf16x2(v[6], v[7]);
            *(uint4*)(base + ((c0 * 2) ^ sw)) = pk;   // 16B-aligned, 2-way max
        }
    }

    const int wm = (wave >> 1) * 32;         // wave tile: 32 f x 64 n
    const int wn = (wave & 1) * 64;

    f32x4 acc[2][4];
#pragma unroll
    for (int mi = 0; mi < 2; ++mi)
#pragma unroll
        for (int nj = 0; nj < 4; ++nj)
            acc[mi][nj] = (f32x4){0.f, 0.f, 0.f, 0.f};

    for (int step = 0; step < NSTEP; ++step) {
        const int ft = step >> 2;
        const int kt = (step & 3) * BK;

        __syncthreads();   // prev step's frag reads done (step 0: Xt ds_writes visible)

        // ---- A tile: 16KB via 2x global_load_lds dwordx4; source pre-swizzled ----
        {
            const __hip_bfloat16* Aft = W2 + (size_t)ft * BF * C_DIM + kt;
#pragma unroll
            for (int j = 0; j < 2; ++j) {
                int s = j * 512 + tid;                   // 16B slot id [0,1024)
                int m = s >> 3, g = s & 7;
                const __hip_bfloat16* gp = Aft + m * C_DIM + ((g ^ (m & 7)) * 8);
                char* lp = (char*)sA + (j * 512 + wave * 64) * 16;  // wave-uniform base
                load_lds16((const void*)gp, (void*)lp);
            }
        }

        __syncthreads();   // staging complete (barrier drains vmcnt for lds-DMA)

        // ---- fragments + MFMA (swizzled reads, ~conflict-free) ----
        bf16x8 af[2][2], bfr[2][4];
#pragma unroll
        for (int kk = 0; kk < 2; ++kk) {
#pragma unroll
            for (int mi = 0; mi < 2; ++mi) {
                int m   = wm + mi * 16 + l15;
                int col = (kk * 64 + l4 * 16) ^ ((m & 7) << 4);
                af[kk][mi] = *(const bf16x8*)(sA + m * 128 + col);
            }
#pragma unroll
            for (int nj = 0; nj < 4; ++nj) {
                int n   = wn + nj * 16 + l15;
                int col = (kt * 2 + kk * 64 + l4 * 16) ^ ((n & 31) << 4);
                bfr[kk][nj] = *(const bf16x8*)(sX + n * 512 + col);
            }
        }
#pragma unroll
        for (int kk = 0; kk < 2; ++kk)
#pragma unroll
            for (int mi = 0; mi < 2; ++mi)
#pragma unroll
                for (int nj = 0; nj < 4; ++nj)
                    acc[mi][nj] = __builtin_amdgcn_mfma_f32_16x16x32_bf16(
                        af[kk][mi], bfr[kk][nj], acc[mi][nj], 0, 0, 0);

        // ---- per-f-tile epilogue: C/D layout col=lane&15, row=(lane>>4)*4+r ----
        if ((step & 3) == 3) {
            float* Oft = Ob + (size_t)(ft * BF) * N_DIM;
#pragma unroll
            for (int mi = 0; mi < 2; ++mi) {
                int mrow = wm + mi * 16 + l4 * 4;
#pragma unroll
                for (int nj = 0; nj < 4; ++nj) {
                    int ncol = wn + nj * 16 + l15;
                    float* op = Oft + (size_t)mrow * N_DIM + ncol;
#pragma unroll
                    for (int r = 0; r < 4; ++r)
                        __builtin_nontemporal_store(acc[mi][nj][r], op + (size_t)r * N_DIM);
                    acc[mi][nj] = (f32x4){0.f, 0.f, 0.f, 0.f};
                }
            }
        }
    }
}

extern "C" void kernel_launch(void* const* d_in, const int* in_sizes, int n_in,
                              void* d_out, int out_size, void* d_ws, size_t ws_size,
                              hipStream_t stream) {
    const float* x   = (const float*)d_in[0];   // [64,256,64,64]
    const float* w   = (const float*)d_in[1];   // [512,256,3,3]
    const float* eps = (const float*)d_in[2];   // [1,512,256,3,3]
    float* out       = (float*)d_out;           // [1,64,512,64,64]
    __hip_bfloat16* w2 = (__hip_bfloat16*)d_ws; // 512*256 bf16 = 256 KB scratch

    prep_w2<<<dim3((F_DIM * C_DIM + 255) / 256), dim3(256), 0, stream>>>(w, eps, w2);
    gemm_kernel<<<dim3(B_DIM * 32), dim3(512), 0, stream>>>(x, w2, out);
}